// Round 10
// baseline (436.702 us; speedup 1.0000x reference)
//
#include <hip/hip_runtime.h>
#include <hip/hip_fp16.h>

#define N 128
#define INF_ 1e9f
#define QNAN_U 0x7FC00000u
typedef unsigned long long ull;

// float -> order-preserving u32 (ascending); NaN marker sorts above all finite
__device__ __forceinline__ unsigned f2ord(float f) {
    unsigned b = __float_as_uint(f);
    return b ^ ((unsigned)((int)b >> 31) | 0x80000000u);
}
__device__ __forceinline__ float ord2f(unsigned k) {
    unsigned b = k ^ ((unsigned)((int)(~k) >> 31) | 0x80000000u);
    return __uint_as_float(b);
}
template <int CTRL>
__device__ __forceinline__ int dppmov(int v) {
    return __builtin_amdgcn_update_dpp(v, v, CTRL, 0xF, 0xF, false);
}
__device__ __forceinline__ int rl(int v, int lane) { return __builtin_amdgcn_readlane(v, lane); }
__device__ __forceinline__ unsigned rlu(unsigned v, int lane) {
    return (unsigned)__builtin_amdgcn_readlane((int)v, lane);
}
__device__ __forceinline__ float rlf(float v, int lane) {
    return __int_as_float(__builtin_amdgcn_readlane(__float_as_int(v), lane));
}
__device__ __forceinline__ unsigned uminu(unsigned a, unsigned b) { return a < b ? a : b; }

// min over each 16-lane group via 4 DPP row_ror levels
#define GMIN16(k) { \
    k = uminu(k, (unsigned)dppmov<0x121>((int)k)); \
    k = uminu(k, (unsigned)dppmov<0x122>((int)k)); \
    k = uminu(k, (unsigned)dppmov<0x124>((int)k)); \
    k = uminu(k, (unsigned)dppmov<0x128>((int)k)); \
}
// global min of the 4 group mins (uniform)
#define GMINALL(k, gmin) { \
    unsigned _g0 = rlu(k, 0), _g1 = rlu(k, 16), _g2 = rlu(k, 32), _g3 = rlu(k, 48); \
    gmin = uminu(uminu(_g0, _g1), uminu(_g2, _g3)); \
}
// read element idx (1-based, 2 per lane) from per-lane register pair
#define RLPAIR_I(r0, r1, idx, dst) { \
    int _ln = ((idx) - 1) >> 1; \
    int _a = rl(r0, _ln), _b = rl(r1, _ln); \
    dst = (((idx) - 1) & 1) ? _b : _a; \
}

// One batch per 64-lane wave. Lane l owns CONSECUTIVE cols c0=2l+1, c1=2l+2 (1-based):
// lowest-lane == lowest-column for tie-breaks; assignment p[] lives in lane registers.
__global__ void __launch_bounds__(64) lsa_solve_kernel(
        const float* __restrict__ x, const float* __restrict__ bias,
        float* __restrict__ out, int B) {
    __shared__ unsigned Cs[N][64];       // packed fp16 costs (= -x), cols (2l, 2l+1)
    __shared__ float u_lds[N + 1];
    __shared__ int   colOf[N + 1];       // row -> col (0 = free row)
    __shared__ int   freeQ[N + 1];       // claim arbitration, then free-row queue

    const int b = blockIdx.x;
    const int l = threadIdx.x;
    const int c0 = 2 * l + 1, c1 = 2 * l + 2;
    const ull mlt = (1ull << l) - 1;
    const float* xb = x + (size_t)b * (N * N);

    // ---- stage costs into LDS: one coalesced float2 per lane per row ----
    #pragma unroll 4
    for (int r = 0; r < N; ++r) {
        const float2 f = *(const float2*)&xb[r * N + 2 * l];
        __half2 h = __floats2half2_rn(-f.x, -f.y);     // minimize -x
        Cs[r][l] = __builtin_bit_cast(unsigned, h);
    }
    u_lds[l] = 0.f;   u_lds[l + 64] = 0.f;
    colOf[l + 1] = 0; colOf[l + 65] = 0;
    freeQ[l] = 0x7FFFFFFF; freeQ[l + 64] = 0x7FFFFFFF;
    if (l == 0) { u_lds[128] = 0.f; colOf[0] = 0; freeQ[128] = 0x7FFFFFFF; }
    __syncthreads();

    // ---- Phase A: column reduction + greedy claim (freeQ doubles as rowOwner) ----
    float m0 = INF_, m1 = INF_; int am0 = 1, am1 = 1;
    #pragma unroll 4
    for (int r = 0; r < N; ++r) {
        __half2 h = __builtin_bit_cast(__half2, Cs[r][l]);
        float f0 = __low2float(h), f1 = __high2float(h);
        if (f0 < m0) { m0 = f0; am0 = r + 1; }
        if (f1 < m1) { m1 = f1; am1 = r + 1; }
    }
    float v0r = m0, v1r = m1;            // v[j] = column minimum
    atomicMin(&freeQ[am0], c0);
    atomicMin(&freeQ[am1], c1);
    __syncthreads();
    int prow0 = (freeQ[am0] == c0) ? am0 : 0;   // p[c0], p[c1] in registers
    int prow1 = (freeQ[am1] == c1) ? am1 : 0;
    if (prow0) colOf[am0] = c0;
    if (prow1) colOf[am1] = c1;
    __syncthreads();

    // ---- Phase B: reduction transfer (Jacobi reads old v; deferred writes) ----
    {
        float pend0 = 0.f, pend1 = 0.f;
        #pragma unroll 2
        for (int r = 1; r <= N; ++r) {
            int j1 = __builtin_amdgcn_readfirstlane(colOf[r]);
            __half2 h = __builtin_bit_cast(__half2, Cs[r - 1][l]);
            float rc0 = __low2float(h)  - v0r;
            float rc1 = __high2float(h) - v1r;
            if (c0 == j1) rc0 = INF_;
            if (c1 == j1) rc1 = INF_;
            unsigned k = uminu(f2ord(rc0), f2ord(rc1));
            GMIN16(k)
            unsigned gmin; GMINALL(k, gmin)
            float m2 = ord2f(gmin);
            if (j1 != 0) {
                if (c0 == j1) pend0 = m2;
                if (c1 == j1) pend1 = m2;
            }
        }
        v0r -= pend0; v1r -= pend1;
    }

    // ---- build free-row queue ----
    int nf;
    {
        int fA = (colOf[l + 1] == 0);
        int fB = (colOf[l + 65] == 0);
        ull bA = __ballot(fA), bB = __ballot(fB);
        int nA = __popcll(bA);
        if (fA) freeQ[__popcll(bA & mlt)] = l + 1;
        if (fB) freeQ[nA + __popcll(bB & mlt)] = l + 65;
        nf = nA + __popcll(bB);
    }
    __syncthreads();

    // ---- Phase C'': ARR with immediate reprocess under hard global budget ----
    {
        int budget = 3 * nf + 16;
        bool stop = false;
        #pragma unroll 1
        for (int kk = 0; kk < nf && !stop; ++kk) {
            int i = __builtin_amdgcn_readfirstlane(freeQ[kk]);
            #pragma unroll 1
            while (i != 0) {
                if (--budget < 0) { stop = true; break; }   // i stays free (colOf[i]==0)
                __half2 h = __builtin_bit_cast(__half2, Cs[i - 1][l]);
                float rc0 = __low2float(h)  - v0r;
                float rc1 = __high2float(h) - v1r;
                unsigned k0 = f2ord(rc0), k1 = f2ord(rc1);
                unsigned klm = uminu(k0, k1);
                int isHi = (k1 < k0) ? 1 : 0;
                unsigned kg = klm;
                GMIN16(kg)
                unsigned gmin; GMINALL(kg, gmin)
                ull bw = __ballot(klm == gmin);
                int wl = (int)__builtin_ctzll(bw);
                int hi1 = rl(isHi, wl);
                int j1 = 2 * wl + 1 + hi1;
                // second-best over all: lane wl contributes its other key
                unsigned oth = (l == wl) ? (hi1 ? k0 : k1) : klm;
                unsigned kg2 = oth;
                GMIN16(kg2)
                unsigned m2o; GMINALL(kg2, m2o)
                if (gmin < m2o) {
                    float d = ord2f(m2o) - ord2f(gmin);
                    if (c0 == j1) v0r -= d;              // v only decreases
                    if (c1 == j1) v1r -= d;
                } else {
                    int pj1; RLPAIR_I(prow0, prow1, j1, pj1)
                    if (pj1 != 0) {                      // tie & occupied: second col
                        ull bw2 = __ballot(oth == m2o);
                        int wl2 = (int)__builtin_ctzll(bw2);
                        int hi2 = (wl2 == wl) ? (hi1 ^ 1) : rl(isHi, wl2);
                        j1 = 2 * wl2 + 1 + hi2;
                    }
                }
                int disp; RLPAIR_I(prow0, prow1, j1, disp)   // old p[j1]
                if (c0 == j1) prow0 = i;
                if (c1 == j1) prow1 = i;
                if (l == 0) {
                    colOf[i] = j1;
                    if (disp != 0) colOf[disp] = 0;
                }
                i = disp;
            }
        }
        __syncthreads();
    }

    // ---- rebuild free-row queue ----
    {
        int fA = (colOf[l + 1] == 0);
        int fB = (colOf[l + 65] == 0);
        ull bA = __ballot(fA), bB = __ballot(fB);
        int nA = __popcll(bA);
        if (fA) freeQ[__popcll(bA & mlt)] = l + 1;
        if (fB) freeQ[nA + __popcll(bB & mlt)] = l + 65;
        nf = nA + __popcll(bB);
    }
    __syncthreads();
    int qv0 = freeQ[l], qv1 = freeQ[l + 64];

    // ---- Phase F: free-row row reduction (sets u; claims argmin col iff free) ----
    #pragma unroll 1
    for (int fi = 0; fi < nf; ++fi) {
        int sl = fi & 63;
        const int i = (fi < 64) ? rl(qv0, sl) : rl(qv1, sl);
        __half2 h = __builtin_bit_cast(__half2, Cs[i - 1][l]);
        float rc0 = __low2float(h)  - v0r;
        float rc1 = __high2float(h) - v1r;
        unsigned k0 = f2ord(rc0), k1 = f2ord(rc1);
        unsigned kl = uminu(k0, k1);
        int isHi = (k1 < k0) ? 1 : 0;
        unsigned kg = kl;
        GMIN16(kg)
        unsigned gmin; GMINALL(kg, gmin)
        ull bw = __ballot(kl == gmin);
        int wl = (int)__builtin_ctzll(bw);
        int hi = rl(isHi, wl);
        int jm = 2 * wl + 1 + hi;
        if (l == 0) u_lds[i] = ord2f(gmin);             // feasible; prepaid first level
        int pm; RLPAIR_I(prow0, prow1, jm, pm)
        if (pm == 0) {
            if (c0 == jm) prow0 = i;
            if (c1 == jm) prow1 = i;
            if (l == 0) colOf[i] = jm;
        }
    }
    __syncthreads();

    // ---- Phase D: u = C - v on assigned pairs (column-owner lanes) ----
    if (prow0) {
        __half2 h = __builtin_bit_cast(__half2, Cs[prow0 - 1][l]);
        u_lds[prow0] = __low2float(h) - v0r;
    }
    if (prow1) {
        __half2 h = __builtin_bit_cast(__half2, Cs[prow1 - 1][l]);
        u_lds[prow1] = __high2float(h) - v1r;
    }
    __syncthreads();

    // ---- rebuild free-row queue for SAP ----
    {
        int fA = (colOf[l + 1] == 0);
        int fB = (colOf[l + 65] == 0);
        ull bA = __ballot(fA), bB = __ballot(fB);
        int nA = __popcll(bA);
        if (fA) freeQ[__popcll(bA & mlt)] = l + 1;
        if (fB) freeQ[nA + __popcll(bB & mlt)] = l + 65;
        nf = nA + __popcll(bB);
    }
    __syncthreads();
    qv0 = freeQ[l]; qv1 = freeQ[l + 64];
    float uprow0 = u_lds[prow0], uprow1 = u_lds[prow1];

    // ---- Phase E: SAP augmentation; speculative prefetch of old-dist winner row ----
    #pragma unroll 1
    for (int fi = 0; fi < nf; ++fi) {
        int sl = fi & 63;
        const int i = (fi < 64) ? rl(qv0, sl) : rl(qv1, sl);

        float dist0 = INF_, dist1 = INF_;    // absolute distances (minv + cum)
        int   way0 = 0, way1 = 0;
        float cumAt0 = 0.f, cumAt1 = 0.f;
        float cum = 0.f;
        float base = -u_lds[i];              // base = cum - u[i0]
        int   jcur = 0, i0 = i;
        unsigned roww = Cs[i - 1][l];        // root row (loop-carried)

        #pragma unroll 1
        for (int it = 0; it <= N; ++it) {
            // mark popped col used (NaN dist excludes it everywhere)
            if (c0 == jcur) { cumAt0 = cum; dist0 = __int_as_float(QNAN_U); }
            if (c1 == jcur) { cumAt1 = cum; dist1 = __int_as_float(QNAN_U); }

            // ---- early reduction over OLD dist (runs during roww's LDS wait) ----
            unsigned k0o = f2ord(dist0), k1o = f2ord(dist1);
            unsigned klo = uminu(k0o, k1o);
            int isHiO = (k1o < k0o) ? 1 : 0;
            int   payO  = isHiO ? ((1 << 8) | prow1) : prow0;
            float upayO = isHiO ? uprow1 : uprow0;
            unsigned kgo = klo;
            GMIN16(kgo)
            unsigned gOld; GMINALL(kgo, gOld)
            ull bwo = __ballot(klo == gOld);
            int wlo_ = (int)__builtin_ctzll(bwo);
            int payow = rl(payO, wlo_);
            float uOld = rlf(upayO, wlo_);
            int jOld = 2 * wlo_ + 1 + ((payow >> 8) & 1);
            int iOld = payow & 0xFF;
            // speculative read of the old-winner's row (in flight through cand chain)
            unsigned wspec = Cs[(iOld > 0 ? iOld : 1) - 1][l];

            // ---- cand compute from roww (first roww use -> waits lgkmcnt here) ----
            float t0 = base - v0r, t1 = base - v1r;
            __half2 h = __builtin_bit_cast(__half2, roww);
            float cand0 = __low2float(h)  + t0;   // C - u[i0] - v[j] + cum
            float cand1 = __high2float(h) + t1;
            if (__float_as_uint(dist0) == QNAN_U) cand0 = __int_as_float(QNAN_U);
            if (__float_as_uint(dist1) == QNAN_U) cand1 = __int_as_float(QNAN_U);

            // ---- cand reduction (same length as the old merged reduction) ----
            unsigned k0c = f2ord(cand0), k1c = f2ord(cand1);
            unsigned klc = uminu(k0c, k1c);
            int isHiC = (k1c < k0c) ? 1 : 0;
            int   payC  = isHiC ? ((1 << 8) | prow1) : prow0;
            float upayC = isHiC ? uprow1 : uprow0;
            unsigned kgc = klc;
            GMIN16(kgc)
            unsigned gCand; GMINALL(kgc, gCand)
            ull bwc = __ballot(klc == gCand);
            int wlc_ = (int)__builtin_ctzll(bwc);
            int paycw = rl(payC, wlc_);
            float uCand = rlf(upayC, wlc_);
            int jCand = 2 * wlc_ + 1 + ((paycw >> 8) & 1);
            int iCand = paycw & 0xFF;

            // ---- scalar merge: global min over old ∪ cand, lowest col on tie ----
            bool oldwin = (gOld < gCand) || (gOld == gCand && jOld < jCand);
            int jprev = jcur;
            cum  = ord2f(oldwin ? gOld : gCand);
            jcur = oldwin ? jOld : jCand;
            i0   = oldwin ? iOld : iCand;
            base = cum - (oldwin ? uOld : uCand);

            // ---- lagging dist/way update (feeds next iter's early reduction) ----
            if (cand0 < dist0) { dist0 = cand0; way0 = jprev; }
            if (cand1 < dist1) { dist1 = cand1; way1 = jprev; }

            if (i0 == 0) break;              // reached a free column
            if (oldwin) roww = wspec;        // speculation hit: row already (nearly) here
            else        roww = Cs[i0 - 1][l];
        }

        // deferred dual updates (pre-walk prow; distinct rows -> no races)
        bool used0 = (__float_as_uint(dist0) == QNAN_U);
        bool used1 = (__float_as_uint(dist1) == QNAN_U);
        if (used0) { float dv = cum - cumAt0; v0r -= dv; u_lds[prow0] += dv; }
        if (used1) { float dv = cum - cumAt1; v1r -= dv; u_lds[prow1] += dv; }
        if (l == 0) u_lds[i] += cum;         // root row
        __syncthreads();

        // register-resident augmenting-path walk (uniform scalar control)
        int j = jcur;
        #pragma unroll 1
        while (j != 0) {
            int idx = j - 1, slw = idx >> 1, hib = idx & 1;
            int w0 = rl(way0, slw), w1 = rl(way1, slw);
            int jn = hib ? w1 : w0;
            int pn;
            if (jn == 0) pn = i;
            else {
                int pidx = jn - 1, slp = pidx >> 1, phb = pidx & 1;
                int p0 = rl(prow0, slp), p1 = rl(prow1, slp);
                pn = phb ? p1 : p0;
            }
            if (c0 == j) prow0 = pn;
            if (c1 == j) prow1 = pn;
            j = jn;
        }
        uprow0 = u_lds[prow0];
        uprow1 = u_lds[prow1];
    }

    // ---- epilogue: out = softmax_row(perm * bias / sqrt(B*n)), float2 stores ----
    colOf[prow0] = c0;
    colOf[prow1] = c1;
    __syncthreads();

    const float inv_norm = rsqrtf((float)B * (float)N);   // ||perm||_2 = sqrt(B*n)
    float* ob = out + (size_t)b * (N * N);
    #pragma unroll 2
    for (int r = 0; r < N; ++r) {
        int jA = __builtin_amdgcn_readfirstlane(colOf[r + 1]);
        float s = bias[r * N + (jA - 1)] * inv_norm;
        float e = __expf(s);
        float inv_d = 1.0f / (127.0f + e);
        float av = e * inv_d;
        float2 w;
        w.x = (c0 == jA) ? av : inv_d;
        w.y = (c1 == jA) ? av : inv_d;
        *(float2*)&ob[r * N + 2 * l] = w;
    }
}

extern "C" void kernel_launch(void* const* d_in, const int* in_sizes, int n_in,
                              void* d_out, int out_size, void* d_ws, size_t ws_size,
                              hipStream_t stream) {
    const float* x    = (const float*)d_in[0];
    const float* bias = (const float*)d_in[1];
    float* out = (float*)d_out;
    int B = in_sizes[0] / (N * N);
    hipLaunchKernelGGL(lsa_solve_kernel, dim3(B), dim3(64), 0, stream, x, bias, out, B);
}

// Round 11
// 269.855 us; speedup vs baseline: 1.6183x; 1.6183x over previous
//
#include <hip/hip_runtime.h>
#include <hip/hip_fp16.h>

#define N 128
#define INF_ 1e9f
#define QNAN_U 0x7FC00000u
typedef unsigned long long ull;

// float -> order-preserving u32 (ascending); NaN marker sorts above all finite
__device__ __forceinline__ unsigned f2ord(float f) {
    unsigned b = __float_as_uint(f);
    return b ^ ((unsigned)((int)b >> 31) | 0x80000000u);
}
__device__ __forceinline__ float ord2f(unsigned k) {
    unsigned b = k ^ ((unsigned)((int)(~k) >> 31) | 0x80000000u);
    return __uint_as_float(b);
}
template <int CTRL>
__device__ __forceinline__ int dppmov(int v) {
    return __builtin_amdgcn_update_dpp(v, v, CTRL, 0xF, 0xF, false);
}
__device__ __forceinline__ int rl(int v, int lane) { return __builtin_amdgcn_readlane(v, lane); }
__device__ __forceinline__ unsigned rlu(unsigned v, int lane) {
    return (unsigned)__builtin_amdgcn_readlane((int)v, lane);
}
__device__ __forceinline__ float rlf(float v, int lane) {
    return __int_as_float(__builtin_amdgcn_readlane(__float_as_int(v), lane));
}
__device__ __forceinline__ unsigned uminu(unsigned a, unsigned b) { return a < b ? a : b; }

// min over each 16-lane group via 4 DPP row_ror levels
#define GMIN16(k) { \
    k = uminu(k, (unsigned)dppmov<0x121>((int)k)); \
    k = uminu(k, (unsigned)dppmov<0x122>((int)k)); \
    k = uminu(k, (unsigned)dppmov<0x124>((int)k)); \
    k = uminu(k, (unsigned)dppmov<0x128>((int)k)); \
}
// global min of the 4 group mins (uniform)
#define GMINALL(k, gmin) { \
    unsigned _g0 = rlu(k, 0), _g1 = rlu(k, 16), _g2 = rlu(k, 32), _g3 = rlu(k, 48); \
    gmin = uminu(uminu(_g0, _g1), uminu(_g2, _g3)); \
}
// read element idx (1-based, 2 per lane) from per-lane register pair
#define RLPAIR_I(r0, r1, idx, dst) { \
    int _ln = ((idx) - 1) >> 1; \
    int _a = rl(r0, _ln), _b = rl(r1, _ln); \
    dst = (((idx) - 1) & 1) ? _b : _a; \
}

// One batch per 64-lane wave. Lane l owns CONSECUTIVE cols c0=2l+1, c1=2l+2 (1-based):
// lowest-lane == lowest-column for tie-breaks; assignment p[] lives in lane registers.
__global__ void __launch_bounds__(64) lsa_solve_kernel(
        const float* __restrict__ x, const float* __restrict__ bias,
        float* __restrict__ out, int B) {
    __shared__ unsigned Cs[N][64];       // packed fp16 costs (= -x), cols (2l, 2l+1)
    __shared__ float u_lds[N + 1];
    __shared__ int   colOf[N + 1];       // row -> col (0 = free row)
    __shared__ int   freeQ[N + 1];       // claim arbitration, then free-row queue

    const int b = blockIdx.x;
    const int l = threadIdx.x;
    const int c0 = 2 * l + 1, c1 = 2 * l + 2;
    const ull mlt = (1ull << l) - 1;
    const float* xb = x + (size_t)b * (N * N);

    // ---- stage costs into LDS: one coalesced float2 per lane per row ----
    #pragma unroll 4
    for (int r = 0; r < N; ++r) {
        const float2 f = *(const float2*)&xb[r * N + 2 * l];
        __half2 h = __floats2half2_rn(-f.x, -f.y);     // minimize -x
        Cs[r][l] = __builtin_bit_cast(unsigned, h);
    }
    u_lds[l] = 0.f;   u_lds[l + 64] = 0.f;
    colOf[l + 1] = 0; colOf[l + 65] = 0;
    freeQ[l] = 0x7FFFFFFF; freeQ[l + 64] = 0x7FFFFFFF;
    if (l == 0) { u_lds[128] = 0.f; colOf[0] = 0; freeQ[128] = 0x7FFFFFFF; }
    __syncthreads();

    // ---- Phase A: column reduction + greedy claim (freeQ doubles as rowOwner) ----
    float m0 = INF_, m1 = INF_; int am0 = 1, am1 = 1;
    #pragma unroll 4
    for (int r = 0; r < N; ++r) {
        __half2 h = __builtin_bit_cast(__half2, Cs[r][l]);
        float f0 = __low2float(h), f1 = __high2float(h);
        if (f0 < m0) { m0 = f0; am0 = r + 1; }
        if (f1 < m1) { m1 = f1; am1 = r + 1; }
    }
    float v0r = m0, v1r = m1;            // v[j] = column minimum
    atomicMin(&freeQ[am0], c0);
    atomicMin(&freeQ[am1], c1);
    __syncthreads();
    int prow0 = (freeQ[am0] == c0) ? am0 : 0;   // p[c0], p[c1] in registers
    int prow1 = (freeQ[am1] == c1) ? am1 : 0;
    if (prow0) colOf[am0] = c0;
    if (prow1) colOf[am1] = c1;
    __syncthreads();

    // ---- Phase B: reduction transfer (Jacobi reads old v; deferred writes) ----
    {
        float pend0 = 0.f, pend1 = 0.f;
        #pragma unroll 2
        for (int r = 1; r <= N; ++r) {
            int j1 = __builtin_amdgcn_readfirstlane(colOf[r]);
            __half2 h = __builtin_bit_cast(__half2, Cs[r - 1][l]);
            float rc0 = __low2float(h)  - v0r;
            float rc1 = __high2float(h) - v1r;
            if (c0 == j1) rc0 = INF_;
            if (c1 == j1) rc1 = INF_;
            unsigned k = uminu(f2ord(rc0), f2ord(rc1));
            GMIN16(k)
            unsigned gmin; GMINALL(k, gmin)
            float m2 = ord2f(gmin);
            if (j1 != 0) {
                if (c0 == j1) pend0 = m2;
                if (c1 == j1) pend1 = m2;
            }
        }
        v0r -= pend0; v1r -= pend1;
    }

    // ---- build free-row queue (rows l+1, l+65 per lane) ----
    int nf;
    {
        int fA = (colOf[l + 1] == 0);
        int fB = (colOf[l + 65] == 0);
        ull bA = __ballot(fA), bB = __ballot(fB);
        int nA = __popcll(bA);
        if (fA) freeQ[__popcll(bA & mlt)] = l + 1;
        if (fB) freeQ[nA + __popcll(bB & mlt)] = l + 65;
        nf = nA + __popcll(bB);
    }
    __syncthreads();

    // ---- Phase C': bounded augmenting row reduction (2 passes, NO in-pass reprocess) ----
    {
        int prv = nf;
        #pragma unroll 1
        for (int pass = 0; pass < 2 && prv > 0; ++pass) {
            int wr = 0;
            #pragma unroll 1
            for (int kk = 0; kk < prv; ++kk) {
                const int i = __builtin_amdgcn_readfirstlane(freeQ[kk]);
                __half2 h = __builtin_bit_cast(__half2, Cs[i - 1][l]);
                float rc0 = __low2float(h)  - v0r;
                float rc1 = __high2float(h) - v1r;
                unsigned k0 = f2ord(rc0), k1 = f2ord(rc1);
                unsigned klm = uminu(k0, k1);
                int isHi = (k1 < k0) ? 1 : 0;          // tie -> low col
                unsigned kg = klm;
                GMIN16(kg)
                unsigned gmin; GMINALL(kg, gmin)
                ull bw = __ballot(klm == gmin);
                int wl = (int)__builtin_ctzll(bw);
                int hi1 = rl(isHi, wl);
                int j1 = 2 * wl + 1 + hi1;
                // second-best over all: lane wl contributes its other key
                unsigned oth = (l == wl) ? (hi1 ? k0 : k1) : klm;
                unsigned kg2 = oth;
                GMIN16(kg2)
                unsigned m2o; GMINALL(kg2, m2o)
                if (gmin < m2o) {
                    float d = ord2f(m2o) - ord2f(gmin);
                    if (c0 == j1) v0r -= d;              // v only decreases
                    if (c1 == j1) v1r -= d;
                } else {
                    int pj1; RLPAIR_I(prow0, prow1, j1, pj1)
                    if (pj1 != 0) {                      // tie & occupied: second col
                        ull bw2 = __ballot(oth == m2o);
                        int wl2 = (int)__builtin_ctzll(bw2);
                        int hi2 = (wl2 == wl) ? (hi1 ^ 1) : rl(isHi, wl2);
                        j1 = 2 * wl2 + 1 + hi2;
                    }
                }
                int disp; RLPAIR_I(prow0, prow1, j1, disp)   // old p[j1]
                if (c0 == j1) prow0 = i;
                if (c1 == j1) prow1 = i;
                if (l == 0) {
                    colOf[i] = j1;
                    if (disp != 0) { colOf[disp] = 0; freeQ[wr] = disp; }  // next pass
                }
                if (disp != 0) ++wr;
            }
            prv = wr;                                   // hard-bounded: <= nf per pass
            __syncthreads();
        }
    }

    // ---- rebuild free-row queue ----
    {
        int fA = (colOf[l + 1] == 0);
        int fB = (colOf[l + 65] == 0);
        ull bA = __ballot(fA), bB = __ballot(fB);
        int nA = __popcll(bA);
        if (fA) freeQ[__popcll(bA & mlt)] = l + 1;
        if (fB) freeQ[nA + __popcll(bB & mlt)] = l + 65;
        nf = nA + __popcll(bB);
    }
    __syncthreads();
    int qv0 = freeQ[l], qv1 = freeQ[l + 64];

    // ---- Phase F: free-row row reduction (sets u; claims argmin col iff free) ----
    #pragma unroll 1
    for (int fi = 0; fi < nf; ++fi) {
        int sl = fi & 63;
        const int i = (fi < 64) ? rl(qv0, sl) : rl(qv1, sl);
        __half2 h = __builtin_bit_cast(__half2, Cs[i - 1][l]);
        float rc0 = __low2float(h)  - v0r;
        float rc1 = __high2float(h) - v1r;
        unsigned k0 = f2ord(rc0), k1 = f2ord(rc1);
        unsigned kl = uminu(k0, k1);
        int isHi = (k1 < k0) ? 1 : 0;
        unsigned kg = kl;
        GMIN16(kg)
        unsigned gmin; GMINALL(kg, gmin)
        ull bw = __ballot(kl == gmin);
        int wl = (int)__builtin_ctzll(bw);
        int hi = rl(isHi, wl);
        int jm = 2 * wl + 1 + hi;
        if (l == 0) u_lds[i] = ord2f(gmin);             // feasible; prepaid first level
        int pm; RLPAIR_I(prow0, prow1, jm, pm)
        if (pm == 0) {
            if (c0 == jm) prow0 = i;
            if (c1 == jm) prow1 = i;
            if (l == 0) colOf[i] = jm;
        }
    }
    __syncthreads();

    // ---- Phase D: u = C - v on assigned pairs (column-owner lanes) ----
    if (prow0) {
        __half2 h = __builtin_bit_cast(__half2, Cs[prow0 - 1][l]);
        u_lds[prow0] = __low2float(h) - v0r;
    }
    if (prow1) {
        __half2 h = __builtin_bit_cast(__half2, Cs[prow1 - 1][l]);
        u_lds[prow1] = __high2float(h) - v1r;
    }
    __syncthreads();

    // ---- rebuild free-row queue for SAP ----
    {
        int fA = (colOf[l + 1] == 0);
        int fB = (colOf[l + 65] == 0);
        ull bA = __ballot(fA), bB = __ballot(fB);
        int nA = __popcll(bA);
        if (fA) freeQ[__popcll(bA & mlt)] = l + 1;
        if (fB) freeQ[nA + __popcll(bB & mlt)] = l + 65;
        nf = nA + __popcll(bB);
    }
    __syncthreads();
    qv0 = freeQ[l]; qv1 = freeQ[l + 64];
    float uprow0 = u_lds[prow0], uprow1 = u_lds[prow1];

    // prefetch first root's row + u (Cs read-only; free-row u untouched by SAP updates)
    unsigned nrootw = 0; float nu = 0.f;
    if (nf > 0) {
        int i0f = rl(qv0, 0);
        nrootw = Cs[i0f - 1][l];
        nu = u_lds[i0f];
    }

    // ---- Phase E: SAP augmentation for remaining free rows (R6 chain + hoists) ----
    #pragma unroll 1
    for (int fi = 0; fi < nf; ++fi) {
        int sl = fi & 63;
        const int i = (fi < 64) ? rl(qv0, sl) : rl(qv1, sl);

        float dist0 = INF_, dist1 = INF_;    // absolute distances (minv + cum)
        int   way0 = 0, way1 = 0;
        float cumAt0 = 0.f, cumAt1 = 0.f;
        float cum = 0.f;
        float base = -nu;                    // base = cum - u[i0]; root prefetched
        int   jcur = 0, i0 = i;
        unsigned roww = nrootw;              // loop-carried current row

        #pragma unroll 1
        for (int it = 0; it <= N; ++it) {
            float t0 = base - v0r, t1 = base - v1r;   // in LDS-wait shadow
            // mark popped col used (NaN dist excludes it everywhere)
            if (c0 == jcur) { cumAt0 = cum; dist0 = __int_as_float(QNAN_U); }
            if (c1 == jcur) { cumAt1 = cum; dist1 = __int_as_float(QNAN_U); }

            __half2 h = __builtin_bit_cast(__half2, roww);
            float cand0 = __low2float(h)  + t0;   // C - u[i0] - v[j] + cum
            float cand1 = __high2float(h) + t1;
            if (cand0 < dist0) { dist0 = cand0; way0 = jcur; }
            if (cand1 < dist1) { dist1 = cand1; way1 = jcur; }

            unsigned k0 = f2ord(dist0), k1 = f2ord(dist1);
            unsigned kl = uminu(k0, k1);
            int isHi = (k1 < k0) ? 1 : 0;
            int   pay  = isHi ? ((1 << 8) | prow1) : prow0;   // (hi<<8)|prow
            float upay = isHi ? uprow1 : uprow0;
            unsigned kg = kl;
            GMIN16(kg)
            unsigned gmin; GMINALL(kg, gmin)
            ull bw = __ballot(kl == gmin);
            int wl = (int)__builtin_ctzll(bw);
            int payw = rl(pay, wl);
            float uw = rlf(upay, wl);
            cum  = ord2f(gmin);
            jcur = 2 * wl + 1 + ((payw >> 8) & 1);
            i0   = payw & 0xFF;
            base = cum - uw;
            if (i0 == 0) break;              // reached a free column
            roww = Cs[i0 - 1][l];            // issue next row read ASAP
        }

        // prefetch next root's row + u BEFORE updates/walk (next root is free:
        // untouched by the u_lds writes below; Cs is read-only)
        if (fi + 1 < nf) {
            int slp = (fi + 1) & 63;
            int inx = (fi + 1 < 64) ? rl(qv0, slp) : rl(qv1, slp);
            nrootw = Cs[inx - 1][l];
            nu = u_lds[inx];
        }

        // deferred dual updates (pre-walk prow; distinct rows -> no LDS races)
        bool used0 = (__float_as_uint(dist0) == QNAN_U);
        bool used1 = (__float_as_uint(dist1) == QNAN_U);
        if (used0) { float dv = cum - cumAt0; v0r -= dv; u_lds[prow0] += dv; }
        if (used1) { float dv = cum - cumAt1; v1r -= dv; u_lds[prow1] += dv; }
        if (l == 0) u_lds[i] += cum;         // root row
        __syncthreads();

        // register-resident augmenting-path walk (uniform scalar control)
        int j = jcur;
        #pragma unroll 1
        while (j != 0) {
            int idx = j - 1, slw = idx >> 1, hib = idx & 1;
            int w0 = rl(way0, slw), w1 = rl(way1, slw);
            int jn = hib ? w1 : w0;
            int pn;
            if (jn == 0) pn = i;
            else {
                int pidx = jn - 1, slp2 = pidx >> 1, phb = pidx & 1;
                int p0 = rl(prow0, slp2), p1 = rl(prow1, slp2);
                pn = phb ? p1 : p0;
            }
            if (c0 == j) prow0 = pn;
            if (c1 == j) prow1 = pn;
            j = jn;
        }
        uprow0 = u_lds[prow0];
        uprow1 = u_lds[prow1];
    }

    // ---- epilogue: out = softmax_row(perm * bias / sqrt(B*n)), float2 stores ----
    colOf[prow0] = c0;
    colOf[prow1] = c1;
    __syncthreads();

    const float inv_norm = rsqrtf((float)B * (float)N);   // ||perm||_2 = sqrt(B*n)
    float* ob = out + (size_t)b * (N * N);
    #pragma unroll 2
    for (int r = 0; r < N; ++r) {
        int jA = __builtin_amdgcn_readfirstlane(colOf[r + 1]);
        float s = bias[r * N + (jA - 1)] * inv_norm;
        float e = __expf(s);
        float inv_d = 1.0f / (127.0f + e);
        float av = e * inv_d;
        float2 w;
        w.x = (c0 == jA) ? av : inv_d;
        w.y = (c1 == jA) ? av : inv_d;
        *(float2*)&ob[r * N + 2 * l] = w;
    }
}

extern "C" void kernel_launch(void* const* d_in, const int* in_sizes, int n_in,
                              void* d_out, int out_size, void* d_ws, size_t ws_size,
                              hipStream_t stream) {
    const float* x    = (const float*)d_in[0];
    const float* bias = (const float*)d_in[1];
    float* out = (float*)d_out;
    int B = in_sizes[0] / (N * N);
    hipLaunchKernelGGL(lsa_solve_kernel, dim3(B), dim3(64), 0, stream, x, bias, out, B);
}